// Round 2
// baseline (227.416 us; speedup 1.0000x reference)
//
#include <hip/hip_runtime.h>
#include <math.h>

// HoughVoting on MI355X — fused single-kernel version (2 dispatches total).
//
// Round-1 (4 kernels) passed bit-exact at 135 us; rocprof showed even a ~15 KB
// harness fill costs ~43 us -> dispatch overhead dominates. This round fuses
// everything into ONE kernel behind a software grid barrier, preceded only by
// a 256 B memset node (zeroes barrier counter / cursors / argmax keys).
//
// Grid 171 blocks x 256 thr: co-resident by construction (<= 22 CUs at max
// packing vs 256 available), so the arrive/spin barrier cannot deadlock.
// All cross-block data uses agent-scope atomics (per-XCD L2 non-coherence).
//
// Numerics: identical __f*_rn op ordering to the round-1 bit-exact kernel.
// Vote counts are exact small integers; argmax via atomicMax on
// key = votes*8192 + (8191 - c)  (max votes, tie-break smallest c ==
// jnp.argmax first-occurrence).

#define GX 80
#define P_TOT 4800
#define EPSF 1e-6f
#define CAP 4800
#define NBLK 171          // 9 classes x 19 candidate-blocks of 256
#define NTHR 256

// ws int-indexed layout (first 256 B zeroed by the memset node)
#define WI_BAR 0          // 1 uint: barrier arrival counter
#define WI_CUR 16         // 10 ints: per-class pixel cursors
#define WI_KEY 32         // 9 ints: per-class argmax keys
// ws float-indexed layout
#define WS_BINS 1024                      // 5 arrays of 10*CAP: u,v,d,px,py
#define BIN_STRIDE (10 * CAP)             // 48000
#define WS_DSUM (WS_BINS + 5 * BIN_STRIDE)  // 241024; 9*4800 floats

__device__ __forceinline__ void gstoref(float* p, float v) {
    __hip_atomic_store(p, v, __ATOMIC_RELAXED, __HIP_MEMORY_SCOPE_AGENT);
}
__device__ __forceinline__ float gloadf(const float* p) {
    return __hip_atomic_load(p, __ATOMIC_RELAXED, __HIP_MEMORY_SCOPE_AGENT);
}
__device__ __forceinline__ int gloadi(const int* p) {
    return __hip_atomic_load(p, __ATOMIC_RELAXED, __HIP_MEMORY_SCOPE_AGENT);
}

// Arrive-and-spin global barrier. Monotone counter: barrier i waits for
// count >= (i+1)*NBLK, so no reset is needed between barriers.
__device__ __forceinline__ void gbar(unsigned* bar, unsigned target) {
    __syncthreads();
    if (threadIdx.x == 0) {
        __hip_atomic_fetch_add(bar, 1u, __ATOMIC_RELEASE, __HIP_MEMORY_SCOPE_AGENT);
        while (__hip_atomic_load(bar, __ATOMIC_ACQUIRE, __HIP_MEMORY_SCOPE_AGENT) < target) {
            __builtin_amdgcn_s_sleep(8);
        }
    }
    __syncthreads();
    __threadfence();   // belt-and-suspenders acquire for all lanes
}

__global__ __launch_bounds__(NTHR) void k_hough(const int* __restrict__ label,
                                                const float* __restrict__ vp,
                                                const float* __restrict__ extents,
                                                const float* __restrict__ meta,
                                                float* __restrict__ out,
                                                float* __restrict__ ws) {
    const int blk = blockIdx.x;
    const int tid = threadIdx.x;
    unsigned* bar = (unsigned*)ws + WI_BAR;
    int* cur = (int*)ws + WI_CUR;
    int* key = (int*)ws + WI_KEY;

    // ---- Phase 0 (block 0 only): zero all 855 output floats (harness poisons
    // d_out to 0xAA; target/weight/domain stay 0, box/pose written in phase 3
    // by this same block, so no cross-block ordering is needed).
    if (blk == 0) {
        for (int t = tid; t < 855; t += NTHR) out[t] = 0.0f;
    }

    // ---- Phase 1: pixel gather + counting-sort into per-class bins.
    {
        int p = blk * NTHR + tid;
        if (p < P_TOT) {
            int i = p / GX, j = p - i * GX;
            int pyc = i * 8, pxc = j * 8;
            int lab = label[pyc * 640 + pxc];
            int r = __hip_atomic_fetch_add(&cur[lab], 1, __ATOMIC_RELAXED,
                                           __HIP_MEMORY_SCOPE_AGENT);
            int pos = lab * CAP + r;
            int base = (pyc * 640 + pxc) * 30 + 3 * lab;
            float u0 = vp[base], v0 = vp[base + 1], w = vp[base + 2];
            w = fminf(fmaxf(w, -3.0f), 3.0f);
            float d = expf(w);
            float nrm = __fadd_rn(
                __fsqrt_rn(__fadd_rn(__fmul_rn(u0, u0), __fmul_rn(v0, v0))), EPSF);
            float u = __fdiv_rn(u0, nrm);
            float v = __fdiv_rn(v0, nrm);
            float* bu = ws + WS_BINS;
            gstoref(&bu[pos], u);
            gstoref(&bu[BIN_STRIDE + pos], v);
            gstoref(&bu[2 * BIN_STRIDE + pos], d);
            gstoref(&bu[3 * BIN_STRIDE + pos], (float)pxc);
            gstoref(&bu[4 * BIN_STRIDE + pos], (float)pyc);
        }
    }
    gbar(bar, NBLK);

    // ---- Phase 2: votes. blk -> (class k = blk/19 + 1, cand block = blk%19).
    {
        const int k = blk / 19 + 1;
        const int cb = blk - (k - 1) * 19;
        const int c = cb * NTHR + tid;
        const int cntk = gloadi(&cur[k]);
        int ci = c / GX, cj = c - ci * GX;
        float cxf = (float)(cj * 8), cyf = (float)(ci * 8);

        const float* bu = ws + WS_BINS + k * CAP;
        const float* bv = bu + BIN_STRIDE;
        const float* bd = bu + 2 * BIN_STRIDE;
        const float* bx = bu + 3 * BIN_STRIDE;
        const float* by = bu + 4 * BIN_STRIDE;

        __shared__ float su[NTHR], sv[NTHR], sd[NTHR], sx[NTHR], sy[NTHR];
        float accn = 0.0f, accd = 0.0f;

        for (int base = 0; base < cntk; base += NTHR) {
            int m = min(NTHR, cntk - base);
            if (tid < m) {
                su[tid] = gloadf(&bu[base + tid]);
                sv[tid] = gloadf(&bv[base + tid]);
                sd[tid] = gloadf(&bd[base + tid]);
                sx[tid] = gloadf(&bx[base + tid]);
                sy[tid] = gloadf(&by[base + tid]);
            }
            __syncthreads();
            #pragma unroll 4
            for (int p = 0; p < m; ++p) {
                float dx = __fsub_rn(cxf, sx[p]);
                float dy = __fsub_rn(cyf, sy[p]);
                float rd2 = __fadd_rn(__fmul_rn(dx, dx), __fmul_rn(dy, dy));
                float rd = __fadd_rn(__fsqrt_rn(rd2), EPSF);
                float num = __fadd_rn(__fmul_rn(su[p], dx), __fmul_rn(sv[p], dy));
                float dot = __fdiv_rn(num, rd);
                if (dot > 0.9f) {
                    accn += 1.0f;
                    accd += sd[p];
                }
            }
            __syncthreads();
        }
        if (c < P_TOT) {
            gstoref(&ws[WS_DSUM + (k - 1) * P_TOT + c], accd);
            int kv = ((int)accn) * 8192 + (8191 - c);
            atomicMax(&key[k - 1], kv);   // device scope by default
        }
    }
    gbar(bar, 2u * NBLK);

    // ---- Phase 3 (block 0, lanes 0..8): epilogue, identical op order to the
    // round-1 bit-exact version.
    if (blk == 0 && tid < 9) {
        int k = tid + 1;
        int kv = gloadi(&key[k - 1]);
        float votes = (float)(kv >> 13);
        int bc = 8191 - (kv & 8191);
        float dsv = gloadf(&ws[WS_DSUM + (k - 1) * P_TOT + bc]);
        float davg = __fdiv_rn(dsv, fmaxf(votes, 1.0f));
        int ci = bc / GX, cj = bc - ci * GX;
        float cx = (float)(cj * 8), cy = (float)(ci * 8);
        float countf = (float)gloadi(&cur[k]);
        bool valid = (votes > 20.0f) &&
                     (votes > __fmul_rn(0.1f, countf)) &&
                     (__fmul_rn(__fmul_rn(countf, 8.0f), 8.0f) > 500.0f);
        float e0 = extents[k * 3 + 0], e1 = extents[k * 3 + 1], e2 = extents[k * 3 + 2];
        float diam = __fadd_rn(
            __fsqrt_rn(__fadd_rn(__fadd_rn(__fmul_rn(e0, e0), __fmul_rn(e1, e1)),
                                 __fmul_rn(e2, e2))),
            EPSF);
        float fx = meta[0], fy = meta[4], ppx = meta[2], ppy = meta[5];
        float dm = fmaxf(davg, EPSF);
        float hx = __fdiv_rn(__fmul_rn(__fmul_rn(0.5f, diam), fx), dm);
        float hy = __fdiv_rn(__fmul_rn(__fmul_rn(0.5f, diam), fy), dm);
        float score = valid ? votes : 0.0f;
        float* brow = out + (k - 1) * 7;        // top_box [1,9,7]
        brow[0] = 0.0f;
        brow[1] = (float)k;
        brow[2] = __fsub_rn(cx, hx);
        brow[3] = __fsub_rn(cy, hy);
        brow[4] = __fadd_rn(cx, hx);
        brow[5] = __fadd_rn(cy, hy);
        brow[6] = score;
        float tx = __fdiv_rn(__fmul_rn(__fsub_rn(cx, ppx), davg), fx);
        float ty = __fdiv_rn(__fmul_rn(__fsub_rn(cy, ppy), davg), fy);
        float* prow = out + 63 + (k - 1) * 7;   // top_pose [1,9,7]
        prow[0] = 1.0f; prow[1] = 0.0f; prow[2] = 0.0f; prow[3] = 0.0f;
        prow[4] = tx; prow[5] = ty; prow[6] = davg;
    }
}

extern "C" void kernel_launch(void* const* d_in, const int* in_sizes, int n_in,
                              void* d_out, int out_size, void* d_ws, size_t ws_size,
                              hipStream_t stream) {
    const int* label = (const int*)d_in[0];       // [1,480,640] int32
    const float* vp = (const float*)d_in[1];      // [1,480,640,30] f32
    const float* extents = (const float*)d_in[2]; // [10,3] f32
    const float* meta = (const float*)d_in[4];    // [1,9] f32
    float* out = (float*)d_out;                   // 855 floats
    float* ws = (float*)d_ws;

    // Zero barrier counter + cursors + argmax keys (single small memset node).
    hipMemsetAsync(d_ws, 0, 256, stream);
    hipLaunchKernelGGL(k_hough, dim3(NBLK), dim3(NTHR), 0, stream,
                       label, vp, extents, meta, out, ws);
}